// Round 17
// baseline (735.393 us; speedup 1.0000x reference)
//
#include <hip/hip_runtime.h>
#include <math.h>

#define N_NODES 50000
#define N_EDGES 800000
#define N_GRAPHS 512
#define SLOPE 0.2f
#define CAP 48   // bucket capacity; degrees ~Poisson(16), P(deg>48)~1e-11
static constexpr float EPS_BN = 1e-5f;

typedef float v2f __attribute__((ext_vector_type(2)));

// ---------------- fused bucket-scatter + layer-0 transform (R14, verified) --------

__global__ __launch_bounds__(256) void scatter_t9_kernel(
    const int* __restrict__ src, const int* __restrict__ dst,
    const float* __restrict__ ea,
    int* __restrict__ cnt, float4* __restrict__ rec,
    const float* __restrict__ x,
    const float* __restrict__ Wl0, const float* __restrict__ bl0,
    const float* __restrict__ Wr0, const float* __restrict__ br0,
    float* __restrict__ xl, float* __restrict__ xr) {
    int t = threadIdx.x;
    int e = blockIdx.x * 256 + t;
    if (e < N_EDGES) {
        int d = dst[e];
        int pos = atomicAdd(&cnt[d], 1);
        if (pos < CAP)
            rec[(size_t)d * CAP + pos] = make_float4(__int_as_float(src[e] * 64),
                                                     ea[e * 3 + 0], ea[e * 3 + 1], ea[e * 3 + 2]);
    }

    int w = t >> 6;
    int k = t & 63;
    v2f wlr[9];
#pragma unroll
    for (int j = 0; j < 9; j++) wlr[j] = (v2f){Wl0[j * 64 + k], Wr0[j * 64 + k]};
    v2f bias = {bl0[k], br0[k]};
    const int NW = gridDim.x * 4;
    for (int n = blockIdx.x * 4 + w; n < N_NODES; n += NW) {
        int un = __builtin_amdgcn_readfirstlane(n);
        const float* __restrict__ hrow = x + (size_t)un * 9;
        float hb[9];
#pragma unroll
        for (int j = 0; j < 9; j++) hb[j] = hrow[j];
        v2f acc = bias;
#pragma unroll
        for (int j = 0; j < 9; j++)
            acc = __builtin_elementwise_fma((v2f){hb[j], hb[j]}, wlr[j], acc);
        xl[(size_t)un * 64 + k] = acc.x;
        xr[(size_t)un * 64 + k] = acc.y;
    }
}

// ---------------- R14 gat body (verbatim macros) ----------------

#define GAT_PROLOGUE()                                                               \
    float4 we0 = *(const float4*)(We + 0 * 64 + k4);                                 \
    float4 we1 = *(const float4*)(We + 64 + k4);                                     \
    float4 we2 = *(const float4*)(We + 128 + k4);                                    \
    float4 at4 = *(const float4*)(att + k4);                                         \
    v2f we0a = {we0.x, we0.y}, we0b = {we0.z, we0.w};                                \
    v2f we1a = {we1.x, we1.y}, we1b = {we1.z, we1.w};                                \
    v2f we2a = {we2.x, we2.y}, we2b = {we2.z, we2.w};                                \
    v2f ata  = {at4.x, at4.y}, atb  = {at4.z, at4.w};                                \
    float4 bo4 = *(const float4*)(bo + k4);                                          \
    float4 g4  = *(const float4*)(bn_g + k4);                                        \
    float4 b4  = *(const float4*)(bn_b + k4);                                        \
    float4 m4  = *(const float4*)(bn_m + k4);                                        \
    float4 v4  = *(const float4*)(bn_v + k4);

#define GAT_EDGE_LOOP()                                                              \
    v2f oAa = {0.f, 0.f}, oAb = {0.f, 0.f};                                          \
    v2f oBa = {0.f, 0.f}, oBb = {0.f, 0.f};                                          \
    float zA = 0.f, zB = 0.f;                                                        \
    for (int c = beg; c < end; c += 8) {                                             \
        int pA = c + q;     bool vA = pA < end; int iA = vA ? pA : beg;              \
        int pB = c + 4 + q; bool vB = pB < end; int iB = vB ? pB : beg;              \
        float4 rA = recP[iA];                                                        \
        float4 rB = recP[iB];                                                        \
        unsigned offA = (unsigned)__float_as_int(rA.x) + k4;                         \
        unsigned offB = (unsigned)__float_as_int(rB.x) + k4;                         \
        float4 xA = *(const float4*)(xl + offA);                                     \
        float4 xB = *(const float4*)(xl + offB);                                     \
        v2f xAa = {xA.x, xA.y}, xAb = {xA.z, xA.w};                                  \
        v2f xBa = {xB.x, xB.y}, xBb = {xB.z, xB.w};                                  \
        v2f tAa = xAa + xra, tAb = xAb + xrb;                                        \
        v2f tBa = xBa + xra, tBb = xBb + xrb;                                        \
        tAa = __builtin_elementwise_fma((v2f){rA.y, rA.y}, we0a, tAa);               \
        tAb = __builtin_elementwise_fma((v2f){rA.y, rA.y}, we0b, tAb);               \
        tBa = __builtin_elementwise_fma((v2f){rB.y, rB.y}, we0a, tBa);               \
        tBb = __builtin_elementwise_fma((v2f){rB.y, rB.y}, we0b, tBb);               \
        tAa = __builtin_elementwise_fma((v2f){rA.z, rA.z}, we1a, tAa);               \
        tAb = __builtin_elementwise_fma((v2f){rA.z, rA.z}, we1b, tAb);               \
        tBa = __builtin_elementwise_fma((v2f){rB.z, rB.z}, we1a, tBa);               \
        tBb = __builtin_elementwise_fma((v2f){rB.z, rB.z}, we1b, tBb);               \
        tAa = __builtin_elementwise_fma((v2f){rA.w, rA.w}, we2a, tAa);               \
        tAb = __builtin_elementwise_fma((v2f){rA.w, rA.w}, we2b, tAb);               \
        tBa = __builtin_elementwise_fma((v2f){rB.w, rB.w}, we2a, tBa);               \
        tBb = __builtin_elementwise_fma((v2f){rB.w, rB.w}, we2b, tBb);               \
        tAa = __builtin_elementwise_max(tAa, tAa * SLOPE);                           \
        tAb = __builtin_elementwise_max(tAb, tAb * SLOPE);                           \
        tBa = __builtin_elementwise_max(tBa, tBa * SLOPE);                           \
        tBb = __builtin_elementwise_max(tBb, tBb * SLOPE);                           \
        v2f dA = ata * tAa; dA = __builtin_elementwise_fma(atb, tAb, dA);            \
        v2f dB = ata * tBa; dB = __builtin_elementwise_fma(atb, tBb, dB);            \
        float accA = dA.x + dA.y;                                                    \
        float accB = dB.x + dB.y;                                                    \
        accA += __shfl_xor(accA, 1, 64);  accB += __shfl_xor(accB, 1, 64);           \
        accA += __shfl_xor(accA, 2, 64);  accB += __shfl_xor(accB, 2, 64);           \
        accA += __shfl_xor(accA, 4, 64);  accB += __shfl_xor(accB, 4, 64);           \
        accA += __shfl_xor(accA, 8, 64);  accB += __shfl_xor(accB, 8, 64);           \
        float peA = vA ? __expf(accA) : 0.f;                                         \
        float peB = vB ? __expf(accB) : 0.f;                                         \
        v2f pA2 = {peA, peA}, pB2 = {peB, peB};                                      \
        oAa = __builtin_elementwise_fma(pA2, xAa, oAa);                              \
        oAb = __builtin_elementwise_fma(pA2, xAb, oAb);                              \
        oBa = __builtin_elementwise_fma(pB2, xBa, oBa);                              \
        oBb = __builtin_elementwise_fma(pB2, xBb, oBb);                              \
        zA += peA; zB += peB;                                                        \
    }                                                                                \
    v2f oa = oAa + oBa, ob = oAb + oBb;                                              \
    float z = zA + zB;                                                               \
    float4 o = make_float4(oa.x, oa.y, ob.x, ob.y);                                  \
    o.x += __shfl_xor(o.x, 16, 64); o.x += __shfl_xor(o.x, 32, 64);                  \
    o.y += __shfl_xor(o.y, 16, 64); o.y += __shfl_xor(o.y, 32, 64);                  \
    o.z += __shfl_xor(o.z, 16, 64); o.z += __shfl_xor(o.z, 32, 64);                  \
    o.w += __shfl_xor(o.w, 16, 64); o.w += __shfl_xor(o.w, 32, 64);                  \
    z += __shfl_xor(z, 16, 64); z += __shfl_xor(z, 32, 64);

#define GAT_BN_RES()                                                                 \
    float zi = 1.0f / fmaxf(z, 1e-16f);                                              \
    float4 res;                                                                      \
    res.x = fmaxf((o.x * zi + bo4.x - m4.x) * (g4.x / sqrtf(v4.x + EPS_BN)) + b4.x, 0.f); \
    res.y = fmaxf((o.y * zi + bo4.y - m4.y) * (g4.y / sqrtf(v4.y + EPS_BN)) + b4.y, 0.f); \
    res.z = fmaxf((o.z * zi + bo4.z - m4.z) * (g4.z / sqrtf(v4.z + EPS_BN)) + b4.z, 0.f); \
    res.w = fmaxf((o.w * zi + bo4.w - m4.w) * (g4.w / sqrtf(v4.w + EPS_BN)) + b4.w, 0.f);

// ---------------- fused gat(i) + WAVE-PRIVATE transform(i+1) -----------------------
// Identical granularity to R14 (256 thr, wave = node). After the gat epilogue the
// wave writes h[n] (64 floats) to its own 1KB LDS slice (no barrier: intra-wave
// ordering) and immediately computes node n's next-layer transform: lane owns col
// pair 2*lane; weight reads are wave-coalesced (W[j][0..127] contiguous at fixed j,
// 32KB stays L1/L2-hot across all 12.5k blocks); h[j] is a uniform LDS broadcast.

__global__ __launch_bounds__(256) void gat_xform_kernel(
    const float* __restrict__ xl, const float* __restrict__ xr,
    const float4* __restrict__ recP, const int* __restrict__ cnt,
    const float* __restrict__ We, const float* __restrict__ att,
    const float* __restrict__ bo,
    const float* __restrict__ bn_g, const float* __restrict__ bn_b,
    const float* __restrict__ bn_m, const float* __restrict__ bn_v,
    const float* __restrict__ Wl, const float* __restrict__ bl,
    const float* __restrict__ Wr, const float* __restrict__ br,
    float* __restrict__ xl_out, float* __restrict__ xr_out) {
    __shared__ float sh[4][64];
    int t = threadIdx.x;
    int w = t >> 6;
    int lane = t & 63;
    int q = lane >> 4;
    int r = lane & 15;
    int k4 = r * 4;
    int n = blockIdx.x * 4 + w;   // grid exact: 12500*4

    GAT_PROLOGUE()
    float4 xq = *(const float4*)(xr + (size_t)n * 64 + k4);
    v2f xra = {xq.x, xq.y}, xrb = {xq.z, xq.w};
    int beg = n * CAP;
    int end = beg + min(cnt[n], CAP);
    GAT_EDGE_LOOP()
    {
        GAT_BN_RES()
        if (q == 0) {
            sh[w][k4 + 0] = res.x;
            sh[w][k4 + 1] = res.y;
            sh[w][k4 + 2] = res.z;
            sh[w][k4 + 3] = res.w;
        }
    }
    // wave-private LDS: intra-wave program order guarantees visibility (compiler
    // inserts lgkmcnt waits); no __syncthreads needed.

    // ---- transform of node n: lane computes cols {2*lane, 2*lane+1} of [xl|xr] ----
    int col0 = 2 * lane;
    const float* __restrict__ Wcol;
    const float* __restrict__ bcol;
    float* __restrict__ outp;
    if (col0 < 64) {
        Wcol = Wl + col0; bcol = bl + col0;
        outp = xl_out + (size_t)n * 64 + col0;
    } else {
        Wcol = Wr + (col0 - 64); bcol = br + (col0 - 64);
        outp = xr_out + (size_t)n * 64 + (col0 - 64);
    }
    v2f acc = {bcol[0], bcol[1]};
    const float* __restrict__ hrow = sh[w];
#pragma unroll 8
    for (int j = 0; j < 64; j++) {
        float hj = hrow[j];
        v2f wv = *((const v2f*)(Wcol + j * 64));
        acc = __builtin_elementwise_fma((v2f){hj, hj}, wv, acc);
    }
    *((v2f*)outp) = acc;
}

// ---------------- final gat (layer 4): R14 gat_fused7 ----------------

__global__ __launch_bounds__(256) void gat_final_kernel(
    const float* __restrict__ xl, const float* __restrict__ xr,
    const float4* __restrict__ recP, const int* __restrict__ cnt,
    const float* __restrict__ We, const float* __restrict__ att,
    const float* __restrict__ bo,
    const float* __restrict__ bn_g, const float* __restrict__ bn_b,
    const float* __restrict__ bn_m, const float* __restrict__ bn_v,
    float* __restrict__ hout) {
    int t = threadIdx.x;
    int w = t >> 6;
    int lane = t & 63;
    int q = lane >> 4;
    int r = lane & 15;
    int k4 = r * 4;
    int n = blockIdx.x * 4 + w;   // grid exact: 12500*4

    GAT_PROLOGUE()
    float4 xq = *(const float4*)(xr + (size_t)n * 64 + k4);
    v2f xra = {xq.x, xq.y}, xrb = {xq.z, xq.w};
    int beg = n * CAP;
    int end = beg + min(cnt[n], CAP);
    GAT_EDGE_LOOP()
    if (q == 0) {
        GAT_BN_RES()
        *(float4*)(hout + (size_t)n * 64 + k4) = res;
    }
}

// ---------------- readout: all-in-one ----------------

__global__ __launch_bounds__(64) void pool_all_kernel(
    const float* __restrict__ h, const int* __restrict__ batch,
    const float* __restrict__ Wjk, const float* __restrict__ bjk,
    const float* __restrict__ Whead, const float* __restrict__ bhead,
    float* __restrict__ out) {
    int g = blockIdx.x;
    int k = threadIdx.x;
    int lo = 0, hi = N_NODES;
    while (lo < hi) { int mid = (lo + hi) >> 1; if (batch[mid] < g) lo = mid + 1; else hi = mid; }
    int s = lo;
    hi = N_NODES;
    while (lo < hi) { int mid = (lo + hi) >> 1; if (batch[mid] < g + 1) lo = mid + 1; else hi = mid; }
    int e = lo;

    float wc = 0.f;
    for (int j = 0; j < 64; j++) wc = fmaf(Wjk[k * 64 + j], Whead[j], wc);
    float bc = bjk[k] * Whead[k];
    for (int off = 32; off > 0; off >>= 1) bc += __shfl_xor(bc, off, 64);

    float acc = 0.f;
    for (int n = s; n < e; ++n) acc += h[(size_t)n * 64 + k];
    float cntf = (float)(e - s);
    acc /= fmaxf(cntf, 1.0f);
    float v = acc * wc;
    for (int off = 32; off > 0; off >>= 1) v += __shfl_xor(v, off, 64);
    if (k == 0) out[g] = v + bc + bhead[0];
}

// ---------------- launch ----------------

extern "C" void kernel_launch(void* const* d_in, const int* in_sizes, int n_in,
                              void* d_out, int out_size, void* d_ws, size_t ws_size,
                              hipStream_t stream) {
    const float* x     = (const float*)d_in[0];
    const float* ea    = (const float*)d_in[1];
    const float* Wl0   = (const float*)d_in[2];
    const float* Wr0   = (const float*)d_in[3];
    const float* bl0   = (const float*)d_in[4];
    const float* br0   = (const float*)d_in[5];
    const float* We0   = (const float*)d_in[6];
    const float* att0  = (const float*)d_in[7];
    const float* bo0   = (const float*)d_in[8];
    const float* Wl    = (const float*)d_in[9];
    const float* Wr    = (const float*)d_in[10];
    const float* bl    = (const float*)d_in[11];
    const float* br    = (const float*)d_in[12];
    const float* We    = (const float*)d_in[13];
    const float* att   = (const float*)d_in[14];
    const float* bo    = (const float*)d_in[15];
    const float* bn_g  = (const float*)d_in[16];
    const float* bn_b  = (const float*)d_in[17];
    const float* bn_m  = (const float*)d_in[18];
    const float* bn_v  = (const float*)d_in[19];
    const float* Wjk   = (const float*)d_in[20];
    const float* bjk   = (const float*)d_in[21];
    const float* Whead = (const float*)d_in[22];
    const float* bhead = (const float*)d_in[23];
    const int* edge_index = (const int*)d_in[24];
    const int* batch      = (const int*)d_in[25];

    const int* srcIdx = edge_index;            // edge_index[0]
    const int* dstIdx = edge_index + N_EDGES;  // edge_index[1]

    char* ws = (char*)d_ws;
    size_t off = 0;
    auto alloc = [&](size_t bytes) -> void* {
        void* p = ws + off;
        off += (bytes + 255) & ~(size_t)255;
        return p;
    };
    float* xlA     = (float*)alloc((size_t)N_NODES * 64 * 4);
    float* xrA     = (float*)alloc((size_t)N_NODES * 64 * 4);
    float* xlB     = (float*)alloc((size_t)N_NODES * 64 * 4);
    float* xrB     = (float*)alloc((size_t)N_NODES * 64 * 4);
    float* hfin    = (float*)alloc((size_t)N_NODES * 64 * 4);
    int*   cnt     = (int*)alloc((size_t)N_NODES * 4);
    float4* recP   = (float4*)alloc((size_t)N_NODES * CAP * 16);  // 38.4 MB

    // ---- bucket build + layer-0 transform (-> xlA/xrA) ----
    hipMemsetAsync(cnt, 0, (size_t)N_NODES * 4, stream);
    scatter_t9_kernel<<<(N_EDGES + 255) / 256, 256, 0, stream>>>(
        srcIdx, dstIdx, ea, cnt, recP, x, Wl0, bl0, Wr0, br0, xlA, xrA);

    const int NBN = N_NODES / 4;   // 12500

    // ---- 4 fused layers: gat(i) + transform(i+1), ping-pong A<->B ----
    // F0: gat layer-0 params (We0, bn row 0), transform stack idx 0: A -> B
    gat_xform_kernel<<<NBN, 256, 0, stream>>>(
        xlA, xrA, recP, cnt, We0, att0, bo0,
        bn_g, bn_b, bn_m, bn_v,
        Wl, bl, Wr, br, xlB, xrB);
    // F1..F3: gat stack idx L-1 (bn row L), transform stack idx L
    for (int L = 1; L < 4; L++) {
        const float* inl = (L & 1) ? xlB : xlA;
        const float* inr = (L & 1) ? xrB : xrA;
        float* outl = (L & 1) ? xlA : xlB;
        float* outr = (L & 1) ? xrA : xrB;
        gat_xform_kernel<<<NBN, 256, 0, stream>>>(
            inl, inr, recP, cnt,
            We + (size_t)(L - 1) * 3 * 64, att + (size_t)(L - 1) * 64,
            bo + (size_t)(L - 1) * 64,
            bn_g + (size_t)L * 64, bn_b + (size_t)L * 64,
            bn_m + (size_t)L * 64, bn_v + (size_t)L * 64,
            Wl + (size_t)L * 64 * 64, bl + (size_t)L * 64,
            Wr + (size_t)L * 64 * 64, br + (size_t)L * 64,
            outl, outr);
    }

    // after F3 (L=3 odd): outputs in xlA/xrA
    // ---- final gat (layer 4): stack idx 3, bn row 4 -> hfin ----
    gat_final_kernel<<<NBN, 256, 0, stream>>>(
        xlA, xrA, recP, cnt,
        We + (size_t)3 * 3 * 64, att + (size_t)3 * 64, bo + (size_t)3 * 64,
        bn_g + (size_t)4 * 64, bn_b + (size_t)4 * 64,
        bn_m + (size_t)4 * 64, bn_v + (size_t)4 * 64,
        hfin);

    // ---- readout ----
    pool_all_kernel<<<N_GRAPHS, 64, 0, stream>>>(hfin, batch, Wjk, bjk, Whead, bhead,
                                                 (float*)d_out);
}

// Round 18
// 498.783 us; speedup vs baseline: 1.4744x; 1.4744x over previous
//
#include <hip/hip_runtime.h>
#include <math.h>

#define N_NODES 50000
#define N_EDGES 800000
#define N_GRAPHS 512
#define SLOPE 0.2f
#define CAP 48   // bucket capacity; degrees ~Binomial(800k,1/50k)~Poisson(16), P(deg>48)~1e-11
static constexpr float EPS_BN = 1e-5f;

typedef float v2f __attribute__((ext_vector_type(2)));

// ---------------- fused bucket-scatter + layer-0 transform ----------------
// Record = {float_bits(src*64), e0, e1, e2} : 16B, ea embedded, src pre-scaled to
// element offset so gat can use 32-bit saddr addressing (1 VALU per gather address).

__global__ __launch_bounds__(256) void scatter_t9_kernel(
    const int* __restrict__ src, const int* __restrict__ dst,
    const float* __restrict__ ea,
    int* __restrict__ cnt, float4* __restrict__ rec,
    const float* __restrict__ x,
    const float* __restrict__ Wl0, const float* __restrict__ bl0,
    const float* __restrict__ Wr0, const float* __restrict__ br0,
    float* __restrict__ xl, float* __restrict__ xr) {
    int t = threadIdx.x;
    int e = blockIdx.x * 256 + t;
    if (e < N_EDGES) {
        int d = dst[e];
        int pos = atomicAdd(&cnt[d], 1);
        if (pos < CAP)
            rec[(size_t)d * CAP + pos] = make_float4(__int_as_float(src[e] * 64),
                                                     ea[e * 3 + 0], ea[e * 3 + 1], ea[e * 3 + 2]);
    }

    // layer-0 transform: grid-stride waves, 4 nodes/block-pass
    int w = t >> 6;
    int k = t & 63;
    v2f wlr[9];
#pragma unroll
    for (int j = 0; j < 9; j++) wlr[j] = (v2f){Wl0[j * 64 + k], Wr0[j * 64 + k]};
    v2f bias = {bl0[k], br0[k]};
    const int NW = gridDim.x * 4;
    for (int n = blockIdx.x * 4 + w; n < N_NODES; n += NW) {
        int un = __builtin_amdgcn_readfirstlane(n);
        const float* __restrict__ hrow = x + (size_t)un * 9;
        float hb[9];
#pragma unroll
        for (int j = 0; j < 9; j++) hb[j] = hrow[j];
        v2f acc = bias;
#pragma unroll
        for (int j = 0; j < 9; j++)
            acc = __builtin_elementwise_fma((v2f){hb[j], hb[j]}, wlr[j], acc);
        xl[(size_t)un * 64 + k] = acc.x;
        xr[(size_t)un * 64 + k] = acc.y;
    }
}

// ---------------- main transform (K=64): LDS-tiled GEMM (verified R10/R11) ------

__global__ __launch_bounds__(256) void transform5_kernel(
    const float* __restrict__ h,
    const float* __restrict__ Wl, const float* __restrict__ bl,
    const float* __restrict__ Wr, const float* __restrict__ br,
    float* __restrict__ xl, float* __restrict__ xr) {
    __shared__ float sAt[64][68];
    __shared__ float sB[64][128];
    int t = threadIdx.x;
    int n0 = blockIdx.x * 64;

#pragma unroll
    for (int i = 0; i < 4; i++) {
        int idx = i * 256 + t;
        int row = idx >> 4;
        int fc  = idx & 15;
        int n = n0 + row;
        float4 v = (n < N_NODES) ? *((const float4*)(h + (size_t)n * 64 + fc * 4))
                                 : make_float4(0.f, 0.f, 0.f, 0.f);
        sAt[fc * 4 + 0][row] = v.x;
        sAt[fc * 4 + 1][row] = v.y;
        sAt[fc * 4 + 2][row] = v.z;
        sAt[fc * 4 + 3][row] = v.w;
    }
#pragma unroll
    for (int i = 0; i < 8; i++) {
        int idx = i * 256 + t;
        int j  = idx >> 5;
        int fc = idx & 31;
        int c  = fc * 4;
        float4 v = (c < 64) ? *((const float4*)(Wl + j * 64 + c))
                            : *((const float4*)(Wr + j * 64 + (c - 64)));
        *((float4*)&sB[j][c]) = v;
    }
    __syncthreads();

    int tx = t & 15, ty = t >> 4;
    int col0 = tx * 8;
    const float* bsrc = (col0 < 64) ? (bl + col0) : (br + (col0 - 64));
    v2f acc[4][4];
#pragma unroll
    for (int r = 0; r < 4; r++)
#pragma unroll
        for (int cc = 0; cc < 4; cc++)
            acc[r][cc] = (v2f){bsrc[cc * 2], bsrc[cc * 2 + 1]};

#pragma unroll 4
    for (int j = 0; j < 64; j++) {
        float a0 = sAt[j][ty * 4 + 0];
        float a1 = sAt[j][ty * 4 + 1];
        float a2 = sAt[j][ty * 4 + 2];
        float a3 = sAt[j][ty * 4 + 3];
        float4 bq0 = *((const float4*)&sB[j][col0]);
        float4 bq1 = *((const float4*)&sB[j][col0 + 4]);
        v2f b0 = {bq0.x, bq0.y}, b1 = {bq0.z, bq0.w};
        v2f b2 = {bq1.x, bq1.y}, b3 = {bq1.z, bq1.w};
        v2f a0v = {a0, a0}, a1v = {a1, a1}, a2v = {a2, a2}, a3v = {a3, a3};
        acc[0][0] = __builtin_elementwise_fma(a0v, b0, acc[0][0]);
        acc[0][1] = __builtin_elementwise_fma(a0v, b1, acc[0][1]);
        acc[0][2] = __builtin_elementwise_fma(a0v, b2, acc[0][2]);
        acc[0][3] = __builtin_elementwise_fma(a0v, b3, acc[0][3]);
        acc[1][0] = __builtin_elementwise_fma(a1v, b0, acc[1][0]);
        acc[1][1] = __builtin_elementwise_fma(a1v, b1, acc[1][1]);
        acc[1][2] = __builtin_elementwise_fma(a1v, b2, acc[1][2]);
        acc[1][3] = __builtin_elementwise_fma(a1v, b3, acc[1][3]);
        acc[2][0] = __builtin_elementwise_fma(a2v, b0, acc[2][0]);
        acc[2][1] = __builtin_elementwise_fma(a2v, b1, acc[2][1]);
        acc[2][2] = __builtin_elementwise_fma(a2v, b2, acc[2][2]);
        acc[2][3] = __builtin_elementwise_fma(a2v, b3, acc[2][3]);
        acc[3][0] = __builtin_elementwise_fma(a3v, b0, acc[3][0]);
        acc[3][1] = __builtin_elementwise_fma(a3v, b1, acc[3][1]);
        acc[3][2] = __builtin_elementwise_fma(a3v, b2, acc[3][2]);
        acc[3][3] = __builtin_elementwise_fma(a3v, b3, acc[3][3]);
    }

#pragma unroll
    for (int r = 0; r < 4; r++) {
        int n = n0 + ty * 4 + r;
        if (n < N_NODES) {
            float4 lo = make_float4(acc[r][0].x, acc[r][0].y, acc[r][1].x, acc[r][1].y);
            float4 hi = make_float4(acc[r][2].x, acc[r][2].y, acc[r][3].x, acc[r][3].y);
            float* dstp = (col0 < 64) ? (xl + (size_t)n * 64 + col0)
                                      : (xr + (size_t)n * 64 + (col0 - 64));
            *((float4*)dstp) = lo;
            *((float4*)(dstp + 4)) = hi;
        }
    }
}

// ---------------- fused GATv2 layer: packed-f32, 8 edges in flight, 32-bit saddr ----

__global__ __launch_bounds__(256) void gat_fused7_kernel(
    const float* __restrict__ xl, const float* __restrict__ xr,
    const float4* __restrict__ recP, const int* __restrict__ cnt,
    const float* __restrict__ We, const float* __restrict__ att,
    const float* __restrict__ bo,
    const float* __restrict__ bn_g, const float* __restrict__ bn_b,
    const float* __restrict__ bn_m, const float* __restrict__ bn_v,
    float* __restrict__ hout) {
    int t = threadIdx.x;
    int w = t >> 6;
    int lane = t & 63;
    int q = lane >> 4;
    int r = lane & 15;
    int k4 = r * 4;
    int n = blockIdx.x * 4 + w;   // grid exact: 12500*4

    float4 we0 = *(const float4*)(We + 0 * 64 + k4);
    float4 we1 = *(const float4*)(We + 64 + k4);
    float4 we2 = *(const float4*)(We + 128 + k4);
    float4 at4 = *(const float4*)(att + k4);
    float4 xq  = *(const float4*)(xr + (size_t)n * 64 + k4);
    v2f we0a = {we0.x, we0.y}, we0b = {we0.z, we0.w};
    v2f we1a = {we1.x, we1.y}, we1b = {we1.z, we1.w};
    v2f we2a = {we2.x, we2.y}, we2b = {we2.z, we2.w};
    v2f ata  = {at4.x, at4.y}, atb  = {at4.z, at4.w};
    v2f xra  = {xq.x, xq.y},   xrb  = {xq.z, xq.w};
    int beg = n * CAP;
    int end = beg + min(cnt[n], CAP);

    v2f oAa = {0.f, 0.f}, oAb = {0.f, 0.f};
    v2f oBa = {0.f, 0.f}, oBb = {0.f, 0.f};
    float zA = 0.f, zB = 0.f;

    for (int c = beg; c < end; c += 8) {
        int pA = c + q;     bool vA = pA < end; int iA = vA ? pA : beg;
        int pB = c + 4 + q; bool vB = pB < end; int iB = vB ? pB : beg;
        float4 rA = recP[iA];
        float4 rB = recP[iB];
        // record .x holds src*64 -> 32-bit element offset (saddr-form loads)
        unsigned offA = (unsigned)__float_as_int(rA.x) + k4;
        unsigned offB = (unsigned)__float_as_int(rB.x) + k4;
        float4 xA = *(const float4*)(xl + offA);
        float4 xB = *(const float4*)(xl + offB);
        v2f xAa = {xA.x, xA.y}, xAb = {xA.z, xA.w};
        v2f xBa = {xB.x, xB.y}, xBb = {xB.z, xB.w};

        v2f tAa = xAa + xra, tAb = xAb + xrb;
        v2f tBa = xBa + xra, tBb = xBb + xrb;
        tAa = __builtin_elementwise_fma((v2f){rA.y, rA.y}, we0a, tAa);
        tAb = __builtin_elementwise_fma((v2f){rA.y, rA.y}, we0b, tAb);
        tBa = __builtin_elementwise_fma((v2f){rB.y, rB.y}, we0a, tBa);
        tBb = __builtin_elementwise_fma((v2f){rB.y, rB.y}, we0b, tBb);
        tAa = __builtin_elementwise_fma((v2f){rA.z, rA.z}, we1a, tAa);
        tAb = __builtin_elementwise_fma((v2f){rA.z, rA.z}, we1b, tAb);
        tBa = __builtin_elementwise_fma((v2f){rB.z, rB.z}, we1a, tBa);
        tBb = __builtin_elementwise_fma((v2f){rB.z, rB.z}, we1b, tBb);
        tAa = __builtin_elementwise_fma((v2f){rA.w, rA.w}, we2a, tAa);
        tAb = __builtin_elementwise_fma((v2f){rA.w, rA.w}, we2b, tAb);
        tBa = __builtin_elementwise_fma((v2f){rB.w, rB.w}, we2a, tBa);
        tBb = __builtin_elementwise_fma((v2f){rB.w, rB.w}, we2b, tBb);

        tAa = __builtin_elementwise_max(tAa, tAa * SLOPE);
        tAb = __builtin_elementwise_max(tAb, tAb * SLOPE);
        tBa = __builtin_elementwise_max(tBa, tBa * SLOPE);
        tBb = __builtin_elementwise_max(tBb, tBb * SLOPE);

        v2f dA = ata * tAa; dA = __builtin_elementwise_fma(atb, tAb, dA);
        v2f dB = ata * tBa; dB = __builtin_elementwise_fma(atb, tBb, dB);
        float accA = dA.x + dA.y;
        float accB = dB.x + dB.y;

        accA += __shfl_xor(accA, 1, 64);  accB += __shfl_xor(accB, 1, 64);
        accA += __shfl_xor(accA, 2, 64);  accB += __shfl_xor(accB, 2, 64);
        accA += __shfl_xor(accA, 4, 64);  accB += __shfl_xor(accB, 4, 64);
        accA += __shfl_xor(accA, 8, 64);  accB += __shfl_xor(accB, 8, 64);

        float peA = vA ? __expf(accA) : 0.f;
        float peB = vB ? __expf(accB) : 0.f;
        v2f pA2 = {peA, peA}, pB2 = {peB, peB};
        oAa = __builtin_elementwise_fma(pA2, xAa, oAa);
        oAb = __builtin_elementwise_fma(pA2, xAb, oAb);
        oBa = __builtin_elementwise_fma(pB2, xBa, oBa);
        oBb = __builtin_elementwise_fma(pB2, xBb, oBb);
        zA += peA; zB += peB;
    }

    v2f oa = oAa + oBa, ob = oAb + oBb;
    float z = zA + zB;
    float4 o = make_float4(oa.x, oa.y, ob.x, ob.y);
    o.x += __shfl_xor(o.x, 16, 64); o.x += __shfl_xor(o.x, 32, 64);
    o.y += __shfl_xor(o.y, 16, 64); o.y += __shfl_xor(o.y, 32, 64);
    o.z += __shfl_xor(o.z, 16, 64); o.z += __shfl_xor(o.z, 32, 64);
    o.w += __shfl_xor(o.w, 16, 64); o.w += __shfl_xor(o.w, 32, 64);
    z += __shfl_xor(z, 16, 64); z += __shfl_xor(z, 32, 64);

    if (q == 0) {
        float zi = 1.0f / fmaxf(z, 1e-16f);
        float4 bo4 = *(const float4*)(bo + k4);
        float4 g4  = *(const float4*)(bn_g + k4);
        float4 b4  = *(const float4*)(bn_b + k4);
        float4 m4  = *(const float4*)(bn_m + k4);
        float4 v4  = *(const float4*)(bn_v + k4);
        float4 res;
        res.x = fmaxf((o.x * zi + bo4.x - m4.x) * (g4.x / sqrtf(v4.x + EPS_BN)) + b4.x, 0.f);
        res.y = fmaxf((o.y * zi + bo4.y - m4.y) * (g4.y / sqrtf(v4.y + EPS_BN)) + b4.y, 0.f);
        res.z = fmaxf((o.z * zi + bo4.z - m4.z) * (g4.z / sqrtf(v4.z + EPS_BN)) + b4.z, 0.f);
        res.w = fmaxf((o.w * zi + bo4.w - m4.w) * (g4.w / sqrtf(v4.w + EPS_BN)) + b4.w, 0.f);
        *(float4*)(hout + (size_t)n * 64 + k4) = res;
    }
}

// ---------------- readout: all-in-one ----------------

__global__ __launch_bounds__(64) void pool_all_kernel(
    const float* __restrict__ h, const int* __restrict__ batch,
    const float* __restrict__ Wjk, const float* __restrict__ bjk,
    const float* __restrict__ Whead, const float* __restrict__ bhead,
    float* __restrict__ out) {
    int g = blockIdx.x;
    int k = threadIdx.x;
    int lo = 0, hi = N_NODES;
    while (lo < hi) { int mid = (lo + hi) >> 1; if (batch[mid] < g) lo = mid + 1; else hi = mid; }
    int s = lo;
    hi = N_NODES;
    while (lo < hi) { int mid = (lo + hi) >> 1; if (batch[mid] < g + 1) lo = mid + 1; else hi = mid; }
    int e = lo;

    float wc = 0.f;
    for (int j = 0; j < 64; j++) wc = fmaf(Wjk[k * 64 + j], Whead[j], wc);
    float bc = bjk[k] * Whead[k];
    for (int off = 32; off > 0; off >>= 1) bc += __shfl_xor(bc, off, 64);

    float acc = 0.f;
    for (int n = s; n < e; ++n) acc += h[(size_t)n * 64 + k];
    float cntf = (float)(e - s);
    acc /= fmaxf(cntf, 1.0f);
    float v = acc * wc;
    for (int off = 32; off > 0; off >>= 1) v += __shfl_xor(v, off, 64);
    if (k == 0) out[g] = v + bc + bhead[0];
}

// ---------------- launch ----------------

extern "C" void kernel_launch(void* const* d_in, const int* in_sizes, int n_in,
                              void* d_out, int out_size, void* d_ws, size_t ws_size,
                              hipStream_t stream) {
    const float* x     = (const float*)d_in[0];
    const float* ea    = (const float*)d_in[1];
    const float* Wl0   = (const float*)d_in[2];
    const float* Wr0   = (const float*)d_in[3];
    const float* bl0   = (const float*)d_in[4];
    const float* br0   = (const float*)d_in[5];
    const float* We0   = (const float*)d_in[6];
    const float* att0  = (const float*)d_in[7];
    const float* bo0   = (const float*)d_in[8];
    const float* Wl    = (const float*)d_in[9];
    const float* Wr    = (const float*)d_in[10];
    const float* bl    = (const float*)d_in[11];
    const float* br    = (const float*)d_in[12];
    const float* We    = (const float*)d_in[13];
    const float* att   = (const float*)d_in[14];
    const float* bo    = (const float*)d_in[15];
    const float* bn_g  = (const float*)d_in[16];
    const float* bn_b  = (const float*)d_in[17];
    const float* bn_m  = (const float*)d_in[18];
    const float* bn_v  = (const float*)d_in[19];
    const float* Wjk   = (const float*)d_in[20];
    const float* bjk   = (const float*)d_in[21];
    const float* Whead = (const float*)d_in[22];
    const float* bhead = (const float*)d_in[23];
    const int* edge_index = (const int*)d_in[24];
    const int* batch      = (const int*)d_in[25];

    const int* srcIdx = edge_index;            // edge_index[0]
    const int* dstIdx = edge_index + N_EDGES;  // edge_index[1]

    char* ws = (char*)d_ws;
    size_t off = 0;
    auto alloc = [&](size_t bytes) -> void* {
        void* p = ws + off;
        off += (bytes + 255) & ~(size_t)255;
        return p;
    };
    float* hA      = (float*)alloc((size_t)N_NODES * 64 * 4);
    float* hB      = (float*)alloc((size_t)N_NODES * 64 * 4);
    float* xlb     = (float*)alloc((size_t)N_NODES * 64 * 4);
    float* xrb     = (float*)alloc((size_t)N_NODES * 64 * 4);
    int*   cnt     = (int*)alloc((size_t)N_NODES * 4);
    float4* recP   = (float4*)alloc((size_t)N_NODES * CAP * 16);  // 38.4 MB

    // ---- fused bucket build + layer-0 transform ----
    hipMemsetAsync(cnt, 0, (size_t)N_NODES * 4, stream);
    scatter_t9_kernel<<<(N_EDGES + 255) / 256, 256, 0, stream>>>(
        srcIdx, dstIdx, ea, cnt, recP, x, Wl0, bl0, Wr0, br0, xlb, xrb);

    const int NBN = N_NODES / 4;               // 12500 (fused gat grid)
    const int NBG = (N_NODES + 63) / 64;       // 782 (GEMM transform grid)

    // ---- layer 0 GAT ----
    gat_fused7_kernel<<<NBN, 256, 0, stream>>>(xlb, xrb, recP, cnt,
                                               We0, att0, bo0,
                                               bn_g, bn_b, bn_m, bn_v, hA);

    // ---- layers 1..4 ----
    float* hcur = hA;
    float* hnext = hB;
    for (int i = 0; i < 4; i++) {
        transform5_kernel<<<NBG, 256, 0, stream>>>(hcur,
            Wl + (size_t)i * 64 * 64, bl + (size_t)i * 64,
            Wr + (size_t)i * 64 * 64, br + (size_t)i * 64,
            xlb, xrb);
        gat_fused7_kernel<<<NBN, 256, 0, stream>>>(xlb, xrb, recP, cnt,
            We + (size_t)i * 3 * 64, att + (size_t)i * 64,
            bo + (size_t)i * 64,
            bn_g + (size_t)(i + 1) * 64, bn_b + (size_t)(i + 1) * 64,
            bn_m + (size_t)(i + 1) * 64, bn_v + (size_t)(i + 1) * 64,
            hnext);
        float* tp = hcur; hcur = hnext; hnext = tp;
    }

    // ---- readout ----
    pool_all_kernel<<<N_GRAPHS, 64, 0, stream>>>(hcur, batch, Wjk, bjk, Whead, bhead,
                                                 (float*)d_out);
}